// Round 7
// baseline (617.387 us; speedup 1.0000x reference)
//
#include <hip/hip_runtime.h>

// Blocks2Matrix, wave-autonomous gather (no barriers in the hot loop).
//
//   values[s, mu, p, q] : s*320 + mu*64 + p*8 + q   (S, 5, 8, 8) f32
//   cg[a, b, m]         : a*25 + b*5 + m            (5, 5, 5)    f32
//   block[R, C] = sum_m cg[R%5, C%5, m] * values[s, m, R/5, C/5]
//   H[sys, i*40+R, j*40+C] += block[R,C]        (direct)
//   H[sys, j*40+C, i*40+R] += block[R,C]        (transpose)
//
// Tile (sy,I,J), local (rr,cc), rr=p*5+a, cc=q*5+b:
//   direct  (i=I,j=J): += sum_m cg[(a*5+b)*5+m] * v[m, p, q]
//   transp  (j=I,i=J): += sum_m cg[(b*5+a)*5+m] * v[m, q, p]
//
// Round-5 lesson: block-cooperative LDS staging = 50 LDS reads / 25 FMA and a
// full vmcnt(0) drain at every per-bin barrier -> stuck at ~220us.
// Now: lane l <-> (p,q)=(l>>3,l&7): values loads are 256B coalesced wave
// loads; cg is entry-invariant so SUM values per bin first (5 adds/entry),
// apply the 125-FMA contraction once per bin (skipped when no entries of
// that parity). One wave per bin, 8 bins/wave, zero barriers in the loop.
// Stores coalesced via 1.28KB wave-private LDS restage (2-way = free).

#define SS      32768
#define NORB    40
#define NSYS    16
#define NATOMS  64
#define NDIM    2560
#define NBINS   (NSYS * NATOMS * NATOMS)   // 65536
#define CAP     16                          // Poisson(1): P(n>16) ~ 1e-14
#define MAXOVF  8192
#define GBLK    2048
#define TPB     256
#define WPB     (TPB / 64)                  // 4 waves/block
#define BPW     (NBINS / (GBLK * WPB))      // 8 bins per wave, exact

// ws layout (bytes):
//   [0,        262144)  counts[NBINS]
//   [262144,   262148)  ovf_count
//   [262272,   327808)  ovf entries int2[MAXOVF]
//   [524288,  4718592)  bins[NBINS*CAP]
#define WS_NEEDED   (524288 + (size_t)NBINS * CAP * 4)

__global__ __launch_bounds__(256) void b2m_fill(
    const int* __restrict__ sys_idx, const int* __restrict__ i_idx,
    const int* __restrict__ j_idx,
    int* __restrict__ counts, int* __restrict__ bins,
    int* __restrict__ ovf_cnt, int2* __restrict__ ovf)
{
    int s = blockIdx.x * blockDim.x + threadIdx.x;
    if (s >= SS) return;
    int sy = sys_idx[s], i = i_idx[s], j = j_idx[s];

    int bd = (sy * NATOMS + i) * NATOMS + j;           // direct tile
    int pos = atomicAdd(&counts[bd], 1);
    if (pos < CAP) bins[bd * CAP + pos] = s;
    else { int o = atomicAdd(ovf_cnt, 1); if (o < MAXOVF) ovf[o] = make_int2(bd, s); }

    int bt = (sy * NATOMS + j) * NATOMS + i;           // transpose tile
    int st = s | 0x10000;
    pos = atomicAdd(&counts[bt], 1);
    if (pos < CAP) bins[bt * CAP + pos] = st;
    else { int o = atomicAdd(ovf_cnt, 1); if (o < MAXOVF) ovf[o] = make_int2(bt, st); }
}

// accumulate one entry's values into the per-parity running sums
#define ENTRY_BODY(ENT) do {                                            \
    int _ent = (ENT);                                                   \
    const float* _vb = values + (size_t)(_ent & 0xFFFF) * 320;          \
    if ((_ent & 0x10000) == 0) {                                        \
        ++nD;                                                           \
        _Pragma("unroll")                                               \
        for (int m = 0; m < 5; ++m) vsD[m] += _vb[m * 64 + lane];       \
    } else {                                                            \
        ++nT;                                                           \
        _Pragma("unroll")                                               \
        for (int m = 0; m < 5; ++m) vsT[m] += _vb[m * 64 + bsl];        \
    }                                                                   \
} while (0)

__global__ __launch_bounds__(TPB) void b2m_gather(
    const float* __restrict__ values, const float* __restrict__ cg,
    const int* __restrict__ counts, const int* __restrict__ bins,
    float* __restrict__ H)
{
    __shared__ float scg[128];
    __shared__ float stage[WPB][320];   // wave-private restage strips

    const int tid  = threadIdx.x;
    const int lane = tid & 63;
    const int w    = tid >> 6;

    if (tid < 125) scg[tid] = cg[tid];
    __syncthreads();                    // only barrier in the kernel

    const int p   = lane >> 3, q = lane & 7;
    const int bsl = (q << 3) | p;       // transposed lane index (q,p)

    // store-phase geometry (bin-invariant): e = it*64 + lane of the 8x40 strip
    int soff[5];
    #pragma unroll
    for (int it = 0; it < 5; ++it) {
        int e = it * 64 + lane;
        int srow = e / 40, scol = e - srow * 40;
        soff[it] = srow * 5 * NDIM + scol;
    }

    const int gw = __builtin_amdgcn_readfirstlane((int)blockIdx.x * WPB + w);
    const int t0 = gw * BPW;
    float* const sw = stage[w];

    for (int t = t0; t < t0 + BPW; ++t) {
        int n = counts[t];              // uniform -> s_load
        if (n > CAP) n = CAP;

        float vsD[5] = {0.f, 0.f, 0.f, 0.f, 0.f};
        float vsT[5] = {0.f, 0.f, 0.f, 0.f, 0.f};
        int nD = 0, nT = 0;

        if (n > 0) {
            int4 e4 = *reinterpret_cast<const int4*>(bins + (size_t)t * CAP);
            ENTRY_BODY(e4.x);
            if (n > 1) ENTRY_BODY(e4.y);
            if (n > 2) ENTRY_BODY(e4.z);
            if (n > 3) ENTRY_BODY(e4.w);
            for (int k = 4; k < n; ++k)          // rare tail, P(n>4)=0.37%
                ENTRY_BODY(bins[(size_t)t * CAP + k]);
        }

        float acc[25];
        #pragma unroll
        for (int i2 = 0; i2 < 25; ++i2) acc[i2] = 0.f;

        if (nD) {                        // uniform branch
            #pragma unroll
            for (int a = 0; a < 5; ++a)
                #pragma unroll
                for (int b = 0; b < 5; ++b)
                    #pragma unroll
                    for (int m = 0; m < 5; ++m)
                        acc[a * 5 + b] = fmaf(scg[(a * 5 + b) * 5 + m], vsD[m], acc[a * 5 + b]);
        }
        if (nT) {
            #pragma unroll
            for (int a = 0; a < 5; ++a)
                #pragma unroll
                for (int b = 0; b < 5; ++b)
                    #pragma unroll
                    for (int m = 0; m < 5; ++m)
                        acc[a * 5 + b] = fmaf(scg[(b * 5 + a) * 5 + m], vsT[m], acc[a * 5 + b]);
        }

        // store tile t: 5 rounds g=a; LDS restage for coalesced 256B stores.
        // Same-wave LDS ops are in-order -> no barrier needed.
        const int jj = t & 63, ii = (t >> 6) & 63, sy = t >> 12;
        float* Hs = H + ((size_t)sy * NDIM + (size_t)ii * NORB) * NDIM + (size_t)jj * NORB;
        #pragma unroll
        for (int g = 0; g < 5; ++g) {
            #pragma unroll
            for (int b = 0; b < 5; ++b)          // banks: 2-way only (free)
                sw[p * 40 + q * 5 + b] = acc[g * 5 + b];
            #pragma unroll
            for (int it = 0; it < 5; ++it)       // rows srow*5+g, cols 0..39
                Hs[(size_t)(soff[it] + g * NDIM)] = sw[it * 64 + lane];
        }
    }
}

__global__ __launch_bounds__(256) void b2m_ovf_apply(
    const float* __restrict__ values, const float* __restrict__ cg,
    const int* __restrict__ ovf_cnt, const int2* __restrict__ ovf,
    float* __restrict__ H)
{
    int n = *ovf_cnt;
    if (n > MAXOVF) n = MAXOVF;
    for (int k = blockIdx.x; k < n; k += gridDim.x) {
        int  bin = ovf[k].x;
        int  ent = ovf[k].y;
        int  s   = ent & 0xFFFF;
        bool tr  = (ent >> 16) != 0;
        int  j = bin & 63, i = (bin >> 6) & 63, sy = bin >> 12;
        const float* vs = values + (size_t)s * 320;
        float* Hs = H + (size_t)sy * NDIM * NDIM;
        for (int e = threadIdx.x; e < 1600; e += blockDim.x) {
            int rr = e / 40, cc = e - rr * 40;
            int R = tr ? cc : rr, C = tr ? rr : cc;
            int pp = R / 5, a = R - pp * 5;
            int qq = C / 5, b = C - qq * 5;
            float v = 0.f;
            for (int m = 0; m < 5; ++m)
                v = fmaf(cg[(a * 5 + b) * 5 + m], vs[m * 64 + pp * 8 + qq], v);
            atomicAdd(Hs + (size_t)(i * NORB + rr) * NDIM + (j * NORB + cc), v);
        }
    }
}

// ---- round-1 fallback (used only if ws_size is too small) ----
__global__ __launch_bounds__(320) void b2m_scatter(
    const float* __restrict__ values, const float* __restrict__ cg,
    const int* __restrict__ sys_idx, const int* __restrict__ i_idx,
    const int* __restrict__ j_idx, float* __restrict__ H)
{
    __shared__ float svv[320];
    __shared__ float scg[125];
    const int s = blockIdx.x, tid = threadIdx.x;
    if (tid < 320) svv[tid] = values[(size_t)s * 320 + tid];
    if (tid < 125) scg[tid] = cg[tid];
    __syncthreads();
    const int sys = sys_idx[s], i = i_idx[s], j = j_idx[s];
    float* Hs = H + (size_t)sys * NDIM * NDIM;
    const int rowbase = i * NORB, colbase = j * NORB;
    #pragma unroll
    for (int it = 0; it < 5; ++it) {
        const int e = tid + it * 320;
        const int r = e / 40, c = e - r * 40;
        const int pp = r / 5, a = r - pp * 5, qq = c / 5, b = c - qq * 5;
        float v = 0.f;
        #pragma unroll
        for (int m = 0; m < 5; ++m)
            v = fmaf(scg[(a * 5 + b) * 5 + m], svv[m * 64 + pp * 8 + qq], v);
        atomicAdd(Hs + (size_t)(rowbase + r) * NDIM + (colbase + c), v);
    }
    #pragma unroll
    for (int it = 0; it < 5; ++it) {
        const int e = tid + it * 320;
        const int c2 = e / 40, r2 = e - c2 * 40;
        const int pp = r2 / 5, a = r2 - pp * 5, qq = c2 / 5, b = c2 - qq * 5;
        float v = 0.f;
        #pragma unroll
        for (int m = 0; m < 5; ++m)
            v = fmaf(scg[(a * 5 + b) * 5 + m], svv[m * 64 + pp * 8 + qq], v);
        atomicAdd(Hs + (size_t)(colbase + c2) * NDIM + (rowbase + r2), v);
    }
}

extern "C" void kernel_launch(void* const* d_in, const int* in_sizes, int n_in,
                              void* d_out, int out_size, void* d_ws, size_t ws_size,
                              hipStream_t stream) {
    const float* values  = (const float*)d_in[0];
    const float* cg      = (const float*)d_in[1];
    const int*   sys_idx = (const int*)d_in[2];
    const int*   i_idx   = (const int*)d_in[3];
    const int*   j_idx   = (const int*)d_in[4];
    float*       H       = (float*)d_out;

    if (ws_size >= WS_NEEDED) {
        char* ws      = (char*)d_ws;
        int*  counts  = (int*)ws;                       // 256 KB
        int*  ovf_cnt = (int*)(ws + 262144);
        int2* ovf     = (int2*)(ws + 262272);
        int*  bins    = (int*)(ws + 524288);

        // zero counts + ovf header (bins are guarded by counts)
        hipMemsetAsync(ws, 0, 262400, stream);

        b2m_fill<<<(SS + 255) / 256, 256, 0, stream>>>(
            sys_idx, i_idx, j_idx, counts, bins, ovf_cnt, ovf);
        b2m_gather<<<GBLK, TPB, 0, stream>>>(values, cg, counts, bins, H);
        b2m_ovf_apply<<<64, 256, 0, stream>>>(values, cg, ovf_cnt, ovf, H);
    } else {
        hipMemsetAsync(H, 0, (size_t)out_size * sizeof(float), stream);
        b2m_scatter<<<SS, 320, 0, stream>>>(values, cg, sys_idx, i_idx, j_idx, H);
    }
}

// Round 8
// 557.917 us; speedup vs baseline: 1.1066x; 1.1066x over previous
//
#include <hip/hip_runtime.h>

// Blocks2Matrix, wave-autonomous gather + 2-bins-ahead value prefetch.
//
//   values[s, mu, p, q] : s*320 + mu*64 + p*8 + q   (S, 5, 8, 8) f32
//   cg[a, b, m]         : a*25 + b*5 + m            (5, 5, 5)    f32
//   block[R, C] = sum_m cg[R%5, C%5, m] * values[s, m, R/5, C/5]
//   H[sys, i*40+R, j*40+C] += block[R,C]        (direct)
//   H[sys, j*40+C, i*40+R] += block[R,C]        (transpose)
//
// Tile (sy,I,J), local (rr,cc), rr=p*5+a, cc=q*5+b:
//   direct  (i=I,j=J): += sum_m cg[(a*5+b)*5+m] * v[m, p, q]
//   transp  (j=I,i=J): += sum_m cg[(b*5+a)*5+m] * v[m, q, p]
//
// r4/r5/r7 all land 220-270us regardless of staging structure -> the common
// cost is the serial per-bin chain counts->bins->values (L2/L3 miss ~900cy)
// with no cross-bin overlap. This version: all metadata scalar-loaded once
// per wave; 8-bin loop fully unrolled with a static 3-slot prefetch buffer
// issuing bin k+2's entry-0 value loads at bin k; empty bins (36.8%) take a
// zero-store fast path; contraction is branch-free (absent parity sums = 0).

#define SS      32768
#define NORB    40
#define NSYS    16
#define NATOMS  64
#define NDIM    2560
#define NBINS   (NSYS * NATOMS * NATOMS)   // 65536
#define CAP     16                          // Poisson(1): P(n>16) ~ 1e-14
#define MAXOVF  8192
#define GBLK    2048
#define TPB     256
#define WPB     (TPB / 64)                  // 4 waves/block
#define BPW     (NBINS / (GBLK * WPB))      // 8 bins per wave, exact

// ws layout (bytes):
//   [0,        262144)  counts[NBINS]
//   [262144,   262148)  ovf_count
//   [262272,   327808)  ovf entries int2[MAXOVF]
//   [524288,  4718592)  bins[NBINS*CAP]
#define WS_NEEDED   (524288 + (size_t)NBINS * CAP * 4)

__global__ __launch_bounds__(256) void b2m_fill(
    const int* __restrict__ sys_idx, const int* __restrict__ i_idx,
    const int* __restrict__ j_idx,
    int* __restrict__ counts, int* __restrict__ bins,
    int* __restrict__ ovf_cnt, int2* __restrict__ ovf)
{
    int s = blockIdx.x * blockDim.x + threadIdx.x;
    if (s >= SS) return;
    int sy = sys_idx[s], i = i_idx[s], j = j_idx[s];

    int bd = (sy * NATOMS + i) * NATOMS + j;           // direct tile
    int pos = atomicAdd(&counts[bd], 1);
    if (pos < CAP) bins[bd * CAP + pos] = s;
    else { int o = atomicAdd(ovf_cnt, 1); if (o < MAXOVF) ovf[o] = make_int2(bd, s); }

    int bt = (sy * NATOMS + j) * NATOMS + i;           // transpose tile
    int st = s | 0x10000;
    pos = atomicAdd(&counts[bt], 1);
    if (pos < CAP) bins[bt * CAP + pos] = st;
    else { int o = atomicAdd(ovf_cnt, 1); if (o < MAXOVF) ovf[o] = make_int2(bt, st); }
}

// add one entry's values (in-place global load) into the parity sums
#define ENTRY_ADD(ENT) do {                                            \
    const int _e = (ENT);                                              \
    const float* _vb = values + (size_t)(_e & 0xFFFF) * 320            \
                       + ((_e & 0x10000) ? bsl : lane);                \
    if ((_e & 0x10000) == 0) {                                         \
        _Pragma("unroll")                                              \
        for (int m = 0; m < 5; ++m) vsD[m] += _vb[m * 64];             \
    } else {                                                           \
        _Pragma("unroll")                                              \
        for (int m = 0; m < 5; ++m) vsT[m] += _vb[m * 64];             \
    }                                                                  \
} while (0)

// issue entry-0 value loads for wave-local bin kk into prefetch slot
#define PV_ISSUE(SLOT, KK)                                             \
    if ((KK) < BPW && nA[KK] > 0) {                                    \
        const int _e0 = eb[KK].x;                                      \
        const float* _vb = values + (size_t)(_e0 & 0xFFFF) * 320       \
                           + ((_e0 & 0x10000) ? bsl : lane);           \
        _Pragma("unroll")                                              \
        for (int m = 0; m < 5; ++m) pvb[SLOT][m] = _vb[m * 64];        \
    }

__global__ __launch_bounds__(TPB) void b2m_gather(
    const float* __restrict__ values, const float* __restrict__ cg,
    const int* __restrict__ counts, const int* __restrict__ bins,
    float* __restrict__ H)
{
    __shared__ __align__(16) float scgp[25 * 8];   // cg rows padded to 8
    __shared__ float stage[WPB][320];              // wave-private restage

    const int tid  = threadIdx.x;
    const int lane = tid & 63;
    const int w    = tid >> 6;

    if (tid < 125) scgp[(tid / 5) * 8 + (tid % 5)] = cg[tid];
    __syncthreads();                    // only barrier in the kernel

    const int p   = lane >> 3, q = lane & 7;
    const int bsl = (q << 3) | p;       // transposed lane index (q,p)

    // store geometry: e = it*64 + lane of the 8-row x 40-col strip group
    int soff[5];
    #pragma unroll
    for (int it = 0; it < 5; ++it) {
        int e = it * 64 + lane;
        int srow = e / 40, scol = e - srow * 40;
        soff[it] = srow * 5 * NDIM + scol;
    }

    const int gw = __builtin_amdgcn_readfirstlane((int)blockIdx.x * WPB + w);
    const int t0 = gw * BPW;
    float* const sw = stage[w];

    // ---- all metadata for this wave's 8 bins, scalar loads ----
    int4 cA = *reinterpret_cast<const int4*>(counts + t0);
    int4 cB = *reinterpret_cast<const int4*>(counts + t0 + 4);
    int nA[8] = {cA.x, cA.y, cA.z, cA.w, cB.x, cB.y, cB.z, cB.w};
    #pragma unroll
    for (int k = 0; k < 8; ++k) if (nA[k] > CAP) nA[k] = CAP;

    int4 eb[8];
    #pragma unroll
    for (int k = 0; k < 8; ++k)
        eb[k] = *reinterpret_cast<const int4*>(bins + (size_t)(t0 + k) * CAP);

    // ---- prologue: prefetch entry-0 values for bins 0,1 ----
    float pvb[3][5];
    PV_ISSUE(0, 0)
    PV_ISSUE(1, 1)

    #pragma unroll
    for (int k = 0; k < BPW; ++k) {
        const int t = t0 + k;

        // issue bin k+2's entry-0 value loads (2 iterations of cover)
        PV_ISSUE((k + 2) % 3, k + 2)

        const int jj = t & 63, ii = (t >> 6) & 63, sy = t >> 12;
        float* Hs = H + ((size_t)sy * NDIM + (size_t)ii * NORB) * NDIM + (size_t)jj * NORB;

        const int n = nA[k];
        if (n == 0) {                   // 36.8% of bins: pure zero store
            #pragma unroll
            for (int g = 0; g < 5; ++g)
                #pragma unroll
                for (int it = 0; it < 5; ++it)
                    Hs[(size_t)(soff[it] + g * NDIM)] = 0.f;
            continue;
        }

        float vsD[5] = {0.f, 0.f, 0.f, 0.f, 0.f};
        float vsT[5] = {0.f, 0.f, 0.f, 0.f, 0.f};

        // entry 0 from the prefetch buffer
        if ((eb[k].x & 0x10000) == 0) {
            #pragma unroll
            for (int m = 0; m < 5; ++m) vsD[m] += pvb[k % 3][m];
        } else {
            #pragma unroll
            for (int m = 0; m < 5; ++m) vsT[m] += pvb[k % 3][m];
        }
        // entries 1..n-1 in place (P(n>=2)=26%)
        if (n > 1) ENTRY_ADD(eb[k].y);
        if (n > 2) ENTRY_ADD(eb[k].z);
        if (n > 3) ENTRY_ADD(eb[k].w);
        for (int kk = 4; kk < n; ++kk)
            ENTRY_ADD(bins[(size_t)t * CAP + kk]);

        // contraction fused with restage + store; absent parity sums are 0
        #pragma unroll
        for (int g = 0; g < 5; ++g) {
            #pragma unroll
            for (int b = 0; b < 5; ++b) {
                const float4 w0 = *reinterpret_cast<const float4*>(&scgp[(g * 5 + b) * 8]);
                const float  w4 = scgp[(g * 5 + b) * 8 + 4];
                const float4 u0 = *reinterpret_cast<const float4*>(&scgp[(b * 5 + g) * 8]);
                const float  u4 = scgp[(b * 5 + g) * 8 + 4];
                float av = fmaf(w0.x, vsD[0],
                           fmaf(w0.y, vsD[1],
                           fmaf(w0.z, vsD[2],
                           fmaf(w0.w, vsD[3], w4 * vsD[4]))));
                av = fmaf(u0.x, vsT[0],
                     fmaf(u0.y, vsT[1],
                     fmaf(u0.z, vsT[2],
                     fmaf(u0.w, vsT[3], fmaf(u4, vsT[4], av)))));
                sw[p * 40 + q * 5 + b] = av;    // 2-way bank alias = free
            }
            #pragma unroll
            for (int it = 0; it < 5; ++it)      // same-wave LDS in-order
                Hs[(size_t)(soff[it] + g * NDIM)] = sw[it * 64 + lane];
        }
    }
}

__global__ __launch_bounds__(256) void b2m_ovf_apply(
    const float* __restrict__ values, const float* __restrict__ cg,
    const int* __restrict__ ovf_cnt, const int2* __restrict__ ovf,
    float* __restrict__ H)
{
    int n = *ovf_cnt;
    if (n > MAXOVF) n = MAXOVF;
    for (int k = blockIdx.x; k < n; k += gridDim.x) {
        int  bin = ovf[k].x;
        int  ent = ovf[k].y;
        int  s   = ent & 0xFFFF;
        bool tr  = (ent >> 16) != 0;
        int  j = bin & 63, i = (bin >> 6) & 63, sy = bin >> 12;
        const float* vs = values + (size_t)s * 320;
        float* Hs = H + (size_t)sy * NDIM * NDIM;
        for (int e = threadIdx.x; e < 1600; e += blockDim.x) {
            int rr = e / 40, cc = e - rr * 40;
            int R = tr ? cc : rr, C = tr ? rr : cc;
            int pp = R / 5, a = R - pp * 5;
            int qq = C / 5, b = C - qq * 5;
            float v = 0.f;
            for (int m = 0; m < 5; ++m)
                v = fmaf(cg[(a * 5 + b) * 5 + m], vs[m * 64 + pp * 8 + qq], v);
            atomicAdd(Hs + (size_t)(i * NORB + rr) * NDIM + (j * NORB + cc), v);
        }
    }
}

// ---- round-1 fallback (used only if ws_size is too small) ----
__global__ __launch_bounds__(320) void b2m_scatter(
    const float* __restrict__ values, const float* __restrict__ cg,
    const int* __restrict__ sys_idx, const int* __restrict__ i_idx,
    const int* __restrict__ j_idx, float* __restrict__ H)
{
    __shared__ float svv[320];
    __shared__ float scg[125];
    const int s = blockIdx.x, tid = threadIdx.x;
    if (tid < 320) svv[tid] = values[(size_t)s * 320 + tid];
    if (tid < 125) scg[tid] = cg[tid];
    __syncthreads();
    const int sys = sys_idx[s], i = i_idx[s], j = j_idx[s];
    float* Hs = H + (size_t)sys * NDIM * NDIM;
    const int rowbase = i * NORB, colbase = j * NORB;
    #pragma unroll
    for (int it = 0; it < 5; ++it) {
        const int e = tid + it * 320;
        const int r = e / 40, c = e - r * 40;
        const int pp = r / 5, a = r - pp * 5, qq = c / 5, b = c - qq * 5;
        float v = 0.f;
        #pragma unroll
        for (int m = 0; m < 5; ++m)
            v = fmaf(scg[(a * 5 + b) * 5 + m], svv[m * 64 + pp * 8 + qq], v);
        atomicAdd(Hs + (size_t)(rowbase + r) * NDIM + (colbase + c), v);
    }
    #pragma unroll
    for (int it = 0; it < 5; ++it) {
        const int e = tid + it * 320;
        const int c2 = e / 40, r2 = e - c2 * 40;
        const int pp = r2 / 5, a = r2 - pp * 5, qq = c2 / 5, b = c2 - qq * 5;
        float v = 0.f;
        #pragma unroll
        for (int m = 0; m < 5; ++m)
            v = fmaf(scg[(a * 5 + b) * 5 + m], svv[m * 64 + pp * 8 + qq], v);
        atomicAdd(Hs + (size_t)(colbase + c2) * NDIM + (rowbase + r2), v);
    }
}

extern "C" void kernel_launch(void* const* d_in, const int* in_sizes, int n_in,
                              void* d_out, int out_size, void* d_ws, size_t ws_size,
                              hipStream_t stream) {
    const float* values  = (const float*)d_in[0];
    const float* cg      = (const float*)d_in[1];
    const int*   sys_idx = (const int*)d_in[2];
    const int*   i_idx   = (const int*)d_in[3];
    const int*   j_idx   = (const int*)d_in[4];
    float*       H       = (float*)d_out;

    if (ws_size >= WS_NEEDED) {
        char* ws      = (char*)d_ws;
        int*  counts  = (int*)ws;                       // 256 KB
        int*  ovf_cnt = (int*)(ws + 262144);
        int2* ovf     = (int2*)(ws + 262272);
        int*  bins    = (int*)(ws + 524288);

        // zero counts + ovf header (bins are guarded by counts)
        hipMemsetAsync(ws, 0, 262400, stream);

        b2m_fill<<<(SS + 255) / 256, 256, 0, stream>>>(
            sys_idx, i_idx, j_idx, counts, bins, ovf_cnt, ovf);
        b2m_gather<<<GBLK, TPB, 0, stream>>>(values, cg, counts, bins, H);
        b2m_ovf_apply<<<64, 256, 0, stream>>>(values, cg, ovf_cnt, ovf, H);
    } else {
        hipMemsetAsync(H, 0, (size_t)out_size * sizeof(float), stream);
        b2m_scatter<<<SS, 320, 0, stream>>>(values, cg, sys_idx, i_idx, j_idx, H);
    }
}